// Round 4
// baseline (758.484 us; speedup 1.0000x reference)
//
#include <hip/hip_runtime.h>
#include <hip/hip_bf16.h>

#define DOUT 128
#define NEG 0.01f

__device__ __forceinline__ float bf2f(unsigned short u) {
    union { unsigned int i; float f; } c; c.i = ((unsigned int)u) << 16; return c.f;
}
__device__ __forceinline__ unsigned short f2bf(float f) {
    union { float f; unsigned int i; } c; c.f = f;
    unsigned int r = c.i + 0x7FFF + ((c.i >> 16) & 1);   // round-to-nearest-even
    return (unsigned short)(r >> 16);
}

// ---------------- GEMM: h = x @ W + b (fp32 vector ALU) + fused s_dst/s_src ----
// x tile staged in LDS once; W streamed from global (L1-hot) with one-chunk-ahead
// prefetch. h stored as bf16 (halves gather traffic downstream); s computed fp32.
#define BM 64

__global__ __launch_bounds__(256)
void gemm_h(const float* __restrict__ x, const float* __restrict__ W,
            const float* __restrict__ b, const float* __restrict__ a_w,
            unsigned short* __restrict__ h, float* __restrict__ s_dst,
            float* __restrict__ s_src, int N)
{
    __shared__ float Xs[BM][DOUT];   // 32 KB
    const int tid = threadIdx.x;
    const int row0 = blockIdx.x * BM;

    // stage x tile: 64x128 floats = 2048 float4, 8 per thread, coalesced
#pragma unroll
    for (int i = 0; i < 8; ++i) {
        int q = i * 256 + tid;
        int r = q >> 5;
        int c = (q & 31) << 2;
        int gn = row0 + r;
        float4 v = make_float4(0.f, 0.f, 0.f, 0.f);
        if (gn < N) v = *(const float4*)&x[(size_t)gn * DOUT + c];
        *(float4*)&Xs[r][c] = v;
    }
    __syncthreads();

    const int dg = (tid & 31) << 2;     // dim base (4 dims)
    const int r0 = (tid >> 5) << 3;     // node base (8 nodes)

    float acc[8][4];
#pragma unroll
    for (int i = 0; i < 8; ++i)
#pragma unroll
        for (int j = 0; j < 4; ++j) acc[i][j] = 0.f;

    float4 wa0 = *(const float4*)&W[(size_t)0 * DOUT + dg];
    float4 wa1 = *(const float4*)&W[(size_t)1 * DOUT + dg];
    float4 wa2 = *(const float4*)&W[(size_t)2 * DOUT + dg];
    float4 wa3 = *(const float4*)&W[(size_t)3 * DOUT + dg];

#pragma unroll
    for (int k = 0; k < DOUT; k += 4) {
        float4 wb0 = wa0, wb1 = wa1, wb2 = wa2, wb3 = wa3;
        if (k + 4 < DOUT) {
            wb0 = *(const float4*)&W[(size_t)(k + 4) * DOUT + dg];
            wb1 = *(const float4*)&W[(size_t)(k + 5) * DOUT + dg];
            wb2 = *(const float4*)&W[(size_t)(k + 6) * DOUT + dg];
            wb3 = *(const float4*)&W[(size_t)(k + 7) * DOUT + dg];
        }
#pragma unroll
        for (int i = 0; i < 8; ++i) {
            float4 xq = *(float4*)&Xs[r0 + i][k];   // wave-broadcast (free)
            acc[i][0] += xq.x * wa0.x + xq.y * wa1.x + xq.z * wa2.x + xq.w * wa3.x;
            acc[i][1] += xq.x * wa0.y + xq.y * wa1.y + xq.z * wa2.y + xq.w * wa3.y;
            acc[i][2] += xq.x * wa0.z + xq.y * wa1.z + xq.z * wa2.z + xq.w * wa3.z;
            acc[i][3] += xq.x * wa0.w + xq.y * wa1.w + xq.z * wa2.w + xq.w * wa3.w;
        }
        wa0 = wb0; wa1 = wb1; wa2 = wb2; wa3 = wb3;
    }

    const float4 bb   = *(const float4*)&b[dg];
    const float4 aw_d = *(const float4*)&a_w[dg];
    const float4 aw_s = *(const float4*)&a_w[DOUT + dg];
#pragma unroll
    for (int i = 0; i < 8; ++i) {
        int gn = row0 + r0 + i;
        float4 o;
        o.x = acc[i][0] + bb.x;
        o.y = acc[i][1] + bb.y;
        o.z = acc[i][2] + bb.z;
        o.w = acc[i][3] + bb.w;
        if (gn < N) {
            ushort4 hb;
            hb.x = f2bf(o.x); hb.y = f2bf(o.y); hb.z = f2bf(o.z); hb.w = f2bf(o.w);
            *(ushort4*)&h[(size_t)gn * DOUT + dg] = hb;
        }
        // fused attention scalars from fp32 accumulators
        float sd = o.x * aw_d.x + o.y * aw_d.y + o.z * aw_d.z + o.w * aw_d.w;
        float ss = o.x * aw_s.x + o.y * aw_s.y + o.z * aw_s.z + o.w * aw_s.w;
#pragma unroll
        for (int off = 16; off; off >>= 1) {
            sd += __shfl_xor(sd, off, 32);
            ss += __shfl_xor(ss, off, 32);
        }
        if ((tid & 31) == 0 && gn < N) { s_dst[gn] = sd; s_src[gn] = ss; }
    }
}

// ---------------- CSR row offsets from sorted edge_dst ----------------
__global__ void build_offsets(const int* __restrict__ edge_dst,
                              int* __restrict__ offsets, int N, int E)
{
    int e = blockIdx.x * blockDim.x + threadIdx.x;
    if (e >= E) return;
    int d = edge_dst[e];
    int prev = (e == 0) ? -1 : edge_dst[e - 1];
    for (int n = prev + 1; n <= d; ++n) offsets[n] = e;
    if (e == E - 1)
        for (int n = d + 1; n <= N; ++n) offsets[n] = E;
}

// ---------------- segment softmax + weighted aggregation (wave per node) ----------------
// pass 3: half-wave (32 lanes) per edge row, bf16x4 (8B) loads, 8 edges in flight.
#define WBUF 256

__global__ __launch_bounds__(256)
void gat_agg(const int* __restrict__ edge_src, const int* __restrict__ offsets,
             const unsigned short* __restrict__ h, const float* __restrict__ s_src,
             const float* __restrict__ s_dst, const float* __restrict__ a_b,
             float* __restrict__ out, int N)
{
    __shared__ float eb_all[4][WBUF];
    __shared__ int   sb_all[4][WBUF];
    const int lane = threadIdx.x & 63;
    const int wv = threadIdx.x >> 6;
    const int n = blockIdx.x * 4 + wv;
    const bool active = (n < N);

    float* eb = eb_all[wv];
    int*   sb = sb_all[wv];

    int start = 0, end = 0;
    float sdn = 0.f;
    if (active) {
        start = offsets[n];
        end = offsets[n + 1];
        sdn = s_dst[n] + a_b[0];
    }
    const int deg = end - start;
    const int cached = deg < WBUF ? deg : WBUF;

    // ---- pass 1: logits (registers) + src cache (LDS) + wave max ----
    float lgr[4];
    float mymax = -3.4e38f;
#pragma unroll
    for (int t = 0; t < 4; ++t) {
        int i = lane + t * 64;
        if (i < cached) {
            int s = edge_src[start + i];
            float lg = sdn + s_src[s];
            lg = lg >= 0.f ? lg : NEG * lg;
            sb[i] = s;
            lgr[t] = lg;
            mymax = fmaxf(mymax, lg);
        }
    }
    for (int i = WBUF + lane; i < deg; i += 64) {     // overflow path
        float lg = sdn + s_src[edge_src[start + i]];
        lg = lg >= 0.f ? lg : NEG * lg;
        mymax = fmaxf(mymax, lg);
    }
#pragma unroll
    for (int o = 32; o; o >>= 1) mymax = fmaxf(mymax, __shfl_xor(mymax, o, 64));

    // ---- pass 2: exp -> LDS, wave sum ----
    float mysum = 0.f;
#pragma unroll
    for (int t = 0; t < 4; ++t) {
        int i = lane + t * 64;
        if (i < cached) {
            float ex = __expf(lgr[t] - mymax);
            eb[i] = ex;
            mysum += ex;
        }
    }
    for (int i = WBUF + lane; i < deg; i += 64) {     // overflow path
        float lg = sdn + s_src[edge_src[start + i]];
        lg = lg >= 0.f ? lg : NEG * lg;
        mysum += __expf(lg - mymax);
    }
#pragma unroll
    for (int o = 32; o; o >>= 1) mysum += __shfl_xor(mysum, o, 64);

    __syncthreads();   // eb/sb visible across lanes

    // ---- pass 3: half-wave per edge, bf16x4 loads, 8 edges per round ----
    const ushort4* __restrict__ h4 = (const ushort4*)h;   // row stride = 32
    const int half = lane >> 5;       // 0 or 1
    const int sub  = lane & 31;       // dims [sub*4, sub*4+4)
    float4 acc = make_float4(0.f, 0.f, 0.f, 0.f);

    int e = 0;
    for (; e + 8 <= cached; e += 8) {
        int i0 = e + half, i1 = e + 2 + half, i2 = e + 4 + half, i3 = e + 6 + half;
        int s0 = sb[i0], s1 = sb[i1], s2 = sb[i2], s3 = sb[i3];
        float w0 = eb[i0], w1 = eb[i1], w2 = eb[i2], w3 = eb[i3];
        ushort4 v0 = h4[(size_t)s0 * 32 + sub];
        ushort4 v1 = h4[(size_t)s1 * 32 + sub];
        ushort4 v2 = h4[(size_t)s2 * 32 + sub];
        ushort4 v3 = h4[(size_t)s3 * 32 + sub];
        acc.x += w0 * bf2f(v0.x); acc.y += w0 * bf2f(v0.y);
        acc.z += w0 * bf2f(v0.z); acc.w += w0 * bf2f(v0.w);
        acc.x += w1 * bf2f(v1.x); acc.y += w1 * bf2f(v1.y);
        acc.z += w1 * bf2f(v1.z); acc.w += w1 * bf2f(v1.w);
        acc.x += w2 * bf2f(v2.x); acc.y += w2 * bf2f(v2.y);
        acc.z += w2 * bf2f(v2.z); acc.w += w2 * bf2f(v2.w);
        acc.x += w3 * bf2f(v3.x); acc.y += w3 * bf2f(v3.y);
        acc.z += w3 * bf2f(v3.z); acc.w += w3 * bf2f(v3.w);
    }
    for (; e < cached; e += 2) {
        int i = e + half;
        if (i < cached) {
            int s = sb[i];
            float w = eb[i];
            ushort4 v = h4[(size_t)s * 32 + sub];
            acc.x += w * bf2f(v.x); acc.y += w * bf2f(v.y);
            acc.z += w * bf2f(v.z); acc.w += w * bf2f(v.w);
        }
    }
    for (int i = cached; i < deg; ++i) {              // overflow path (half 0 only)
        if (half == 0) {
            int s = edge_src[start + i];
            float lg = sdn + s_src[s];
            lg = lg >= 0.f ? lg : NEG * lg;
            float w = __expf(lg - mymax);
            ushort4 v = h4[(size_t)s * 32 + sub];
            acc.x += w * bf2f(v.x); acc.y += w * bf2f(v.y);
            acc.z += w * bf2f(v.z); acc.w += w * bf2f(v.w);
        }
    }

    // combine the two half-wave partials
    acc.x += __shfl_xor(acc.x, 32, 64);
    acc.y += __shfl_xor(acc.y, 32, 64);
    acc.z += __shfl_xor(acc.z, 32, 64);
    acc.w += __shfl_xor(acc.w, 32, 64);

    if (active && half == 0) {
        const float inv = 1.f / fmaxf(mysum, 1e-16f);
        float4 o;
        o.x = acc.x * inv; o.y = acc.y * inv; o.z = acc.z * inv; o.w = acc.w * inv;
        ((float4*)out)[(size_t)n * 32 + sub] = o;
    }
}

extern "C" void kernel_launch(void* const* d_in, const int* in_sizes, int n_in,
                              void* d_out, int out_size, void* d_ws, size_t ws_size,
                              hipStream_t stream)
{
    const float* x        = (const float*)d_in[0];
    const int*   edge_src = (const int*)d_in[1];
    const int*   edge_dst = (const int*)d_in[2];
    const float* W        = (const float*)d_in[3];
    const float* b        = (const float*)d_in[4];
    const float* a_w      = (const float*)d_in[5];
    const float* a_b      = (const float*)d_in[6];
    const int N = in_sizes[0] / DOUT;
    const int E = in_sizes[1];
    float* out = (float*)d_out;

    char* ws = (char*)d_ws;
    unsigned short* h = (unsigned short*)ws;  ws += (size_t)N * DOUT * sizeof(unsigned short);
    float* s_dst   = (float*)ws;  ws += (size_t)N * sizeof(float);
    float* s_src   = (float*)ws;  ws += (size_t)N * sizeof(float);
    int*   offsets = (int*)ws;    ws += (size_t)(N + 1) * sizeof(int);

    gemm_h<<<(N + BM - 1) / BM, 256, 0, stream>>>(x, W, b, a_w, h, s_dst, s_src, N);
    build_offsets<<<(E + 255) / 256, 256, 0, stream>>>(edge_dst, offsets, N, E);
    gat_agg<<<(N + 3) / 4, 256, 0, stream>>>(edge_src, offsets, h, s_src, s_dst, a_b, out, N);
}

// Round 5
// 158.671 us; speedup vs baseline: 4.7802x; 4.7802x over previous
//
#include <hip/hip_runtime.h>
#include <hip/hip_bf16.h>

#define DOUT 128
#define NEG 0.01f

__device__ __forceinline__ float bf2f(unsigned short u) {
    union { unsigned int i; float f; } c; c.i = ((unsigned int)u) << 16; return c.f;
}
__device__ __forceinline__ unsigned short f2bf(float f) {
    union { float f; unsigned int i; } c; c.f = f;
    unsigned int r = c.i + 0x7FFF + ((c.i >> 16) & 1);   // round-to-nearest-even
    return (unsigned short)(r >> 16);
}

// ---------------- GEMM: h = x @ W + b (fp32 vector ALU) + fused s_dst/s_src ----
// x tile staged in LDS once (single barrier); W streamed from global (L1-hot).
// NO unroll pragma / manual prefetch on the k-loop: full unroll spilled to
// scratch at VGPR=256 (R3 post-mortem: 600us, 1.5GB scratch traffic).
#define BM 64

__global__ __launch_bounds__(256)
void gemm_h(const float* __restrict__ x, const float* __restrict__ W,
            const float* __restrict__ b, const float* __restrict__ a_w,
            unsigned short* __restrict__ h, float* __restrict__ s_dst,
            float* __restrict__ s_src, int N)
{
    __shared__ float Xs[BM][DOUT];   // 32 KB
    const int tid = threadIdx.x;
    const int row0 = blockIdx.x * BM;

    // stage x tile: 64x128 floats = 2048 float4, 8 per thread, coalesced
#pragma unroll
    for (int i = 0; i < 8; ++i) {
        int q = i * 256 + tid;
        int r = q >> 5;
        int c = (q & 31) << 2;
        int gn = row0 + r;
        float4 v = make_float4(0.f, 0.f, 0.f, 0.f);
        if (gn < N) v = *(const float4*)&x[(size_t)gn * DOUT + c];
        *(float4*)&Xs[r][c] = v;
    }
    __syncthreads();

    const int dg = (tid & 31) << 2;     // dim base (4 dims)
    const int r0 = (tid >> 5) << 3;     // node base (8 nodes)

    float acc[8][4];
#pragma unroll
    for (int i = 0; i < 8; ++i)
#pragma unroll
        for (int j = 0; j < 4; ++j) acc[i][j] = 0.f;

    for (int k = 0; k < DOUT; k += 4) {
        // 4 independent W row loads (L1/L2-hot after first touch)
        float4 w0 = *(const float4*)&W[(size_t)(k + 0) * DOUT + dg];
        float4 w1 = *(const float4*)&W[(size_t)(k + 1) * DOUT + dg];
        float4 w2 = *(const float4*)&W[(size_t)(k + 2) * DOUT + dg];
        float4 w3 = *(const float4*)&W[(size_t)(k + 3) * DOUT + dg];
#pragma unroll
        for (int i = 0; i < 8; ++i) {
            float4 xq = *(float4*)&Xs[r0 + i][k];   // wave-broadcast (free)
            acc[i][0] += xq.x * w0.x + xq.y * w1.x + xq.z * w2.x + xq.w * w3.x;
            acc[i][1] += xq.x * w0.y + xq.y * w1.y + xq.z * w2.y + xq.w * w3.y;
            acc[i][2] += xq.x * w0.z + xq.y * w1.z + xq.z * w2.z + xq.w * w3.z;
            acc[i][3] += xq.x * w0.w + xq.y * w1.w + xq.z * w2.w + xq.w * w3.w;
        }
    }

    const float4 bb   = *(const float4*)&b[dg];
    const float4 aw_d = *(const float4*)&a_w[dg];
    const float4 aw_s = *(const float4*)&a_w[DOUT + dg];
#pragma unroll
    for (int i = 0; i < 8; ++i) {
        int gn = row0 + r0 + i;
        float4 o;
        o.x = acc[i][0] + bb.x;
        o.y = acc[i][1] + bb.y;
        o.z = acc[i][2] + bb.z;
        o.w = acc[i][3] + bb.w;
        if (gn < N) {
            ushort4 hb;
            hb.x = f2bf(o.x); hb.y = f2bf(o.y); hb.z = f2bf(o.z); hb.w = f2bf(o.w);
            *(ushort4*)&h[(size_t)gn * DOUT + dg] = hb;
        }
        // fused attention scalars from fp32 accumulators
        float sd = o.x * aw_d.x + o.y * aw_d.y + o.z * aw_d.z + o.w * aw_d.w;
        float ss = o.x * aw_s.x + o.y * aw_s.y + o.z * aw_s.z + o.w * aw_s.w;
#pragma unroll
        for (int off = 16; off; off >>= 1) {
            sd += __shfl_xor(sd, off, 32);
            ss += __shfl_xor(ss, off, 32);
        }
        if ((tid & 31) == 0 && gn < N) { s_dst[gn] = sd; s_src[gn] = ss; }
    }
}

// ---------------- CSR row offsets from sorted edge_dst ----------------
__global__ void build_offsets(const int* __restrict__ edge_dst,
                              int* __restrict__ offsets, int N, int E)
{
    int e = blockIdx.x * blockDim.x + threadIdx.x;
    if (e >= E) return;
    int d = edge_dst[e];
    int prev = (e == 0) ? -1 : edge_dst[e - 1];
    for (int n = prev + 1; n <= d; ++n) offsets[n] = e;
    if (e == E - 1)
        for (int n = d + 1; n <= N; ++n) offsets[n] = E;
}

// ---------------- segment softmax + weighted aggregation (wave per node) ----------------
// pass 3: half-wave (32 lanes) per edge row, bf16x4 (8B) loads, 8 edges in flight.
#define WBUF 256

__global__ __launch_bounds__(256)
void gat_agg(const int* __restrict__ edge_src, const int* __restrict__ offsets,
             const unsigned short* __restrict__ h, const float* __restrict__ s_src,
             const float* __restrict__ s_dst, const float* __restrict__ a_b,
             float* __restrict__ out, int N)
{
    __shared__ float eb_all[4][WBUF];
    __shared__ int   sb_all[4][WBUF];
    const int lane = threadIdx.x & 63;
    const int wv = threadIdx.x >> 6;
    const int n = blockIdx.x * 4 + wv;
    const bool active = (n < N);

    float* eb = eb_all[wv];
    int*   sb = sb_all[wv];

    int start = 0, end = 0;
    float sdn = 0.f;
    if (active) {
        start = offsets[n];
        end = offsets[n + 1];
        sdn = s_dst[n] + a_b[0];
    }
    const int deg = end - start;
    const int cached = deg < WBUF ? deg : WBUF;

    // ---- pass 1: logits (registers) + src cache (LDS) + wave max ----
    float lgr[4];
    float mymax = -3.4e38f;
#pragma unroll
    for (int t = 0; t < 4; ++t) {
        int i = lane + t * 64;
        if (i < cached) {
            int s = edge_src[start + i];
            float lg = sdn + s_src[s];
            lg = lg >= 0.f ? lg : NEG * lg;
            sb[i] = s;
            lgr[t] = lg;
            mymax = fmaxf(mymax, lg);
        }
    }
    for (int i = WBUF + lane; i < deg; i += 64) {     // overflow path
        float lg = sdn + s_src[edge_src[start + i]];
        lg = lg >= 0.f ? lg : NEG * lg;
        mymax = fmaxf(mymax, lg);
    }
#pragma unroll
    for (int o = 32; o; o >>= 1) mymax = fmaxf(mymax, __shfl_xor(mymax, o, 64));

    // ---- pass 2: exp -> LDS, wave sum ----
    float mysum = 0.f;
#pragma unroll
    for (int t = 0; t < 4; ++t) {
        int i = lane + t * 64;
        if (i < cached) {
            float ex = __expf(lgr[t] - mymax);
            eb[i] = ex;
            mysum += ex;
        }
    }
    for (int i = WBUF + lane; i < deg; i += 64) {     // overflow path
        float lg = sdn + s_src[edge_src[start + i]];
        lg = lg >= 0.f ? lg : NEG * lg;
        mysum += __expf(lg - mymax);
    }
#pragma unroll
    for (int o = 32; o; o >>= 1) mysum += __shfl_xor(mysum, o, 64);

    __syncthreads();   // eb/sb visible across lanes

    // ---- pass 3: half-wave per edge, bf16x4 loads, 8 edges per round ----
    const ushort4* __restrict__ h4 = (const ushort4*)h;   // row stride = 32
    const int half = lane >> 5;       // 0 or 1
    const int sub  = lane & 31;       // dims [sub*4, sub*4+4)
    float4 acc = make_float4(0.f, 0.f, 0.f, 0.f);

    int e = 0;
    for (; e + 8 <= cached; e += 8) {
        int i0 = e + half, i1 = e + 2 + half, i2 = e + 4 + half, i3 = e + 6 + half;
        int s0 = sb[i0], s1 = sb[i1], s2 = sb[i2], s3 = sb[i3];
        float w0 = eb[i0], w1 = eb[i1], w2 = eb[i2], w3 = eb[i3];
        ushort4 v0 = h4[(size_t)s0 * 32 + sub];
        ushort4 v1 = h4[(size_t)s1 * 32 + sub];
        ushort4 v2 = h4[(size_t)s2 * 32 + sub];
        ushort4 v3 = h4[(size_t)s3 * 32 + sub];
        acc.x += w0 * bf2f(v0.x); acc.y += w0 * bf2f(v0.y);
        acc.z += w0 * bf2f(v0.z); acc.w += w0 * bf2f(v0.w);
        acc.x += w1 * bf2f(v1.x); acc.y += w1 * bf2f(v1.y);
        acc.z += w1 * bf2f(v1.z); acc.w += w1 * bf2f(v1.w);
        acc.x += w2 * bf2f(v2.x); acc.y += w2 * bf2f(v2.y);
        acc.z += w2 * bf2f(v2.z); acc.w += w2 * bf2f(v2.w);
        acc.x += w3 * bf2f(v3.x); acc.y += w3 * bf2f(v3.y);
        acc.z += w3 * bf2f(v3.z); acc.w += w3 * bf2f(v3.w);
    }
    for (; e < cached; e += 2) {
        int i = e + half;
        if (i < cached) {
            int s = sb[i];
            float w = eb[i];
            ushort4 v = h4[(size_t)s * 32 + sub];
            acc.x += w * bf2f(v.x); acc.y += w * bf2f(v.y);
            acc.z += w * bf2f(v.z); acc.w += w * bf2f(v.w);
        }
    }
    for (int i = cached; i < deg; ++i) {              // overflow path (half 0 only)
        if (half == 0) {
            int s = edge_src[start + i];
            float lg = sdn + s_src[s];
            lg = lg >= 0.f ? lg : NEG * lg;
            float w = __expf(lg - mymax);
            ushort4 v = h4[(size_t)s * 32 + sub];
            acc.x += w * bf2f(v.x); acc.y += w * bf2f(v.y);
            acc.z += w * bf2f(v.z); acc.w += w * bf2f(v.w);
        }
    }

    // combine the two half-wave partials
    acc.x += __shfl_xor(acc.x, 32, 64);
    acc.y += __shfl_xor(acc.y, 32, 64);
    acc.z += __shfl_xor(acc.z, 32, 64);
    acc.w += __shfl_xor(acc.w, 32, 64);

    if (active && half == 0) {
        const float inv = 1.f / fmaxf(mysum, 1e-16f);
        float4 o;
        o.x = acc.x * inv; o.y = acc.y * inv; o.z = acc.z * inv; o.w = acc.w * inv;
        ((float4*)out)[(size_t)n * 32 + sub] = o;
    }
}

extern "C" void kernel_launch(void* const* d_in, const int* in_sizes, int n_in,
                              void* d_out, int out_size, void* d_ws, size_t ws_size,
                              hipStream_t stream)
{
    const float* x        = (const float*)d_in[0];
    const int*   edge_src = (const int*)d_in[1];
    const int*   edge_dst = (const int*)d_in[2];
    const float* W        = (const float*)d_in[3];
    const float* b        = (const float*)d_in[4];
    const float* a_w      = (const float*)d_in[5];
    const float* a_b      = (const float*)d_in[6];
    const int N = in_sizes[0] / DOUT;
    const int E = in_sizes[1];
    float* out = (float*)d_out;

    char* ws = (char*)d_ws;
    unsigned short* h = (unsigned short*)ws;  ws += (size_t)N * DOUT * sizeof(unsigned short);
    float* s_dst   = (float*)ws;  ws += (size_t)N * sizeof(float);
    float* s_src   = (float*)ws;  ws += (size_t)N * sizeof(float);
    int*   offsets = (int*)ws;    ws += (size_t)(N + 1) * sizeof(int);

    gemm_h<<<(N + BM - 1) / BM, 256, 0, stream>>>(x, W, b, a_w, h, s_dst, s_src, N);
    build_offsets<<<(E + 255) / 256, 256, 0, stream>>>(edge_dst, offsets, N, E);
    gat_agg<<<(N + 3) / 4, 256, 0, stream>>>(edge_src, offsets, h, s_src, s_dst, a_b, out, N);
}